// Round 12
// baseline (298.146 us; speedup 1.0000x reference)
//
#include <hip/hip_runtime.h>
#include <hip/hip_bf16.h>

// GCN encoder: 2x GCNConv (sym-norm, self-loops) + ReLU + row L2 normalize.
// N=50000, E=800000, IN=128, HID=256, OUT=256.
// Aggregate-first: A1=agg(x_bf16); H1=relu(A1@W1+b1); A2=agg(H1);
// out=rownorm(A2@W2+b2). r3-form aggs + NONTEMPORAL gather loads (L1 bypass
// experiment: agg hypothesized L1-MSHR-bound), pi-permuted H1 columns,
// MFMA bf16 GEMMs with fused epilogues.

#define NNODE 50000
#define FDIM 256
#define SCAN_CHUNK 2048
#define CAST_BLOCKS 3125   // N*128/8/256
#define WCONV_BLOCKS 48    // (16+32)*256/256

typedef __attribute__((ext_vector_type(8))) short short8;   // 8 bf16 (4 VGPRs)
typedef __attribute__((ext_vector_type(4))) float f32x4;    // MFMA acc
typedef __attribute__((ext_vector_type(2))) unsigned int u32x2;

__device__ __forceinline__ float bflo(unsigned int u) {
    union { unsigned int i; float f; } c;
    c.i = u << 16;
    return c.f;
}
__device__ __forceinline__ float bfhi(unsigned int u) {
    union { unsigned int i; float f; } c;
    c.i = u & 0xFFFF0000u;
    return c.f;
}
__device__ __forceinline__ unsigned short f2bf(float f) {
    __hip_bfloat16 h = __float2bfloat16(f);  // RTN
    return *reinterpret_cast<unsigned short*>(&h);
}
__device__ __forceinline__ unsigned int pk(float lo, float hi) {
    return (unsigned int)f2bf(lo) | ((unsigned int)f2bf(hi) << 16);
}

// ---- prep: cast x->bf16, repack W1/W2, count degrees (independent jobs) --
// Wf2 uses permuted k: position k holds true feature f(k)=(k&~63)|((k&3)<<4)|((k>>2)&15)
// matching gemm1's packed epilogue position map p(f)=(f&~63)|((f&15)<<2)|((f>>4)&3).
__global__ __launch_bounds__(256) void prep_kernel(
    const float* __restrict__ x, unsigned int* __restrict__ xb,
    const float* __restrict__ W1, unsigned short* __restrict__ Wf1,
    const float* __restrict__ W2, unsigned short* __restrict__ Wf2,
    const int* __restrict__ ei, int* __restrict__ counts, int E) {
    int b = blockIdx.x, t = threadIdx.x;
    if (b < CAST_BLOCKS) {            // x[50000][128] fp32 -> bf16
        int i = b * 256 + t;          // 8 floats per thread, exact fit
        const float4* xf = reinterpret_cast<const float4*>(x);
        float4 p = xf[2 * i], q = xf[2 * i + 1];
        uint4 o;
        o.x = pk(p.x, p.y); o.y = pk(p.z, p.w);
        o.z = pk(q.x, q.y); o.w = pk(q.z, q.w);
        reinterpret_cast<uint4*>(xb)[i] = o;
    } else if (b < CAST_BLOCKS + WCONV_BLOCKS) {
        int idx = (b - CAST_BLOCKS) * 256 + t;
        const float* W;
        unsigned short* Wf;
        bool perm;
        if (idx < 16 * 256) { W = W1; Wf = Wf1; perm = false; }
        else { idx -= 16 * 256; W = W2; Wf = Wf2; perm = true; }
        int g = idx >> 8, c = idx & 255;
        unsigned short vals[8];
#pragma unroll
        for (int j = 0; j < 8; ++j) {
            int k = 8 * g + j;
            int f = perm ? ((k & ~63) | ((k & 3) << 4) | ((k >> 2) & 15)) : k;
            vals[j] = f2bf(W[(size_t)f * 256 + c]);
        }
        *reinterpret_cast<ushort4*>(&Wf[(size_t)idx * 8]) =
            make_ushort4(vals[0], vals[1], vals[2], vals[3]);
        *reinterpret_cast<ushort4*>(&Wf[(size_t)idx * 8 + 4]) =
            make_ushort4(vals[4], vals[5], vals[6], vals[7]);
    } else {                           // degree count
        int e = (b - CAST_BLOCKS - WCONV_BLOCKS) * 256 + t;
        if (e < E) atomicAdd(&counts[ei[E + e]], 1);
    }
}

// ---- scan: part1 per-chunk sums; part3 inlines the bsum scan (NB<=64) ---
__global__ __launch_bounds__(256) void scan_part1(const int* __restrict__ counts,
                                                  int* __restrict__ bsum, int n) {
    __shared__ int ws[4];
    int b = blockIdx.x, t = threadIdx.x;
    int base = b * SCAN_CHUNK + t * 8;
    int s = 0;
#pragma unroll
    for (int j = 0; j < 8; ++j) {
        int i = base + j;
        if (i < n) s += counts[i];
    }
#pragma unroll
    for (int off = 32; off >= 1; off >>= 1) s += __shfl_xor(s, off, 64);
    if ((t & 63) == 0) ws[t >> 6] = s;
    __syncthreads();
    if (t == 0) bsum[b] = ws[0] + ws[1] + ws[2] + ws[3];
}

__global__ __launch_bounds__(256) void scan_part3(const int* __restrict__ counts,
                                                  const int* __restrict__ bsum,
                                                  int* __restrict__ row_ptr,
                                                  int* __restrict__ cursor,
                                                  float* __restrict__ dinv,
                                                  int n, int nb) {
    __shared__ int ws[4];
    __shared__ int s_boff, s_total;
    int b = blockIdx.x, t = threadIdx.x, lane = t & 63, wid = t >> 6;
    if (t < 64) {  // wave 0: scan bsum (nb <= 64)
        int v = (t < nb) ? bsum[t] : 0;
        int incl = v;
#pragma unroll
        for (int off = 1; off < 64; off <<= 1) {
            int u = __shfl_up(incl, off, 64);
            if (t >= off) incl += u;
        }
        if (t == b) s_boff = incl - v;
        if (t == nb - 1) s_total = incl;
    }
    __syncthreads();
    if (b == 0 && t == 0) row_ptr[n] = s_total;

    int base = b * SCAN_CHUNK + t * 8;
    int v[8];
    int s = 0;
#pragma unroll
    for (int j = 0; j < 8; ++j) {
        int i = base + j;
        v[j] = (i < n) ? counts[i] : 0;
        s += v[j];
    }
    int incl = s;
#pragma unroll
    for (int off = 1; off < 64; off <<= 1) {
        int u = __shfl_up(incl, off, 64);
        if (lane >= off) incl += u;
    }
    if (lane == 63) ws[wid] = incl;
    __syncthreads();
    int woff = 0;
    for (int u = 0; u < wid; ++u) woff += ws[u];
    int ex = s_boff + woff + incl - s;
#pragma unroll
    for (int j = 0; j < 8; ++j) {
        int i = base + j;
        if (i < n) {
            row_ptr[i] = ex;
            cursor[i] = ex;
            dinv[i] = rsqrtf((float)(v[j] + 1));  // +1 self-loop
        }
        ex += v[j];
    }
}

// edata[pos] = {src, dinv[src]*dinv[dst]} (norm precomputed; r9 showed a
// dependent dinv[src] load in the gather chain costs ~15 us)
__global__ void fill_kernel(const int* __restrict__ ei, const float* __restrict__ dinv,
                            int* __restrict__ cursor, int2* __restrict__ edata, int E) {
    int e = blockIdx.x * blockDim.x + threadIdx.x;
    if (e < E) {
        int s = ei[e];
        int d = ei[E + e];
        int pos = atomicAdd(&cursor[d], 1);
        float nm = dinv[s] * dinv[d];
        edata[pos] = make_int2(s, __float_as_int(nm));
    }
}

// ---- agg1: A1[i] = sum nm*xb[src] + dinv_i^2*xb[i]  (128 feats, 256B rows)
// Gather loads are NONTEMPORAL (nt): bypass L1 allocation -> more misses in
// flight if the agg is L1-MSHR-bound (r11 model).
__global__ __launch_bounds__(256) void agg1_kernel(const unsigned int* __restrict__ xb,
                                                   const int* __restrict__ rowp,
                                                   const int2* __restrict__ edata,
                                                   const float* __restrict__ dinv,
                                                   unsigned int* __restrict__ A1, int n) {
    int node = (blockIdx.x * blockDim.x + threadIdx.x) >> 6;
    int lane = threadIdx.x & 63;
    if (node >= n) return;
    float di = dinv[node];
    float d2 = di * di;
    unsigned int sv = xb[(size_t)node * 64 + lane];
    float a0 = bflo(sv) * d2, a1 = bfhi(sv) * d2;
    int beg = rowp[node], end = rowp[node + 1];
#pragma unroll 8
    for (int e = beg; e < end; ++e) {
        int2 ed = edata[e];
        float nm = __int_as_float(ed.y);
        unsigned int v = __builtin_nontemporal_load(&xb[(size_t)ed.x * 64 + lane]);
        a0 = fmaf(bflo(v), nm, a0);
        a1 = fmaf(bfhi(v), nm, a1);
    }
    A1[(size_t)node * 64 + lane] = pk(a0, a1);
}

// ---- agg2: A2[i] = sum nm*hb[src] + dinv_i^2*hb[i]  (256 feats, 512B rows)
__global__ __launch_bounds__(256) void agg2_kernel(const uint2* __restrict__ hb,
                                                   const int* __restrict__ rowp,
                                                   const int2* __restrict__ edata,
                                                   const float* __restrict__ dinv,
                                                   uint2* __restrict__ A2, int n) {
    int node = (blockIdx.x * blockDim.x + threadIdx.x) >> 6;
    int lane = threadIdx.x & 63;
    if (node >= n) return;
    float di = dinv[node];
    float d2 = di * di;
    uint2 sv = hb[(size_t)node * 64 + lane];
    float a0 = bflo(sv.x) * d2, a1 = bfhi(sv.x) * d2;
    float a2 = bflo(sv.y) * d2, a3 = bfhi(sv.y) * d2;
    int beg = rowp[node], end = rowp[node + 1];
#pragma unroll 8
    for (int e = beg; e < end; ++e) {
        int2 ed = edata[e];
        float nm = __int_as_float(ed.y);
        u32x2 v = __builtin_nontemporal_load(
            reinterpret_cast<const u32x2*>(&hb[(size_t)ed.x * 64 + lane]));
        a0 = fmaf(bflo(v.x), nm, a0);
        a1 = fmaf(bfhi(v.x), nm, a1);
        a2 = fmaf(bflo(v.y), nm, a2);
        a3 = fmaf(bfhi(v.y), nm, a3);
    }
    uint2 o;
    o.x = pk(a0, a1);
    o.y = pk(a2, a3);
    A2[(size_t)node * 64 + lane] = o;
}

// ---- MFMA GEMM + fused epilogue: out = f(A[n,K] @ W[K,256] + bias) ------
// BM=64, BN=256, 4 waves; wave w: rows[0,64) x cols[64w,64w+64).
// EPI 0: relu -> bf16 H in pi-permuted column order (packed uint2 stores).
// EPI 1: row L2-normalize -> f32 out (true order, nontemporal).
template <int K, int EPI>
__global__ __launch_bounds__(256) void gemm_fused(const unsigned short* __restrict__ A,
                                                  const unsigned short* __restrict__ Wf,
                                                  const float* __restrict__ bias,
                                                  void* __restrict__ outp, int n) {
    __shared__ unsigned short As[64 * K];
    __shared__ __align__(16) float ssred[64][4];
    int t = threadIdx.x;
    int row0 = blockIdx.x * 64;

#pragma unroll
    for (int i = 0; i < (64 * K) / (8 * 256); ++i) {
        int o = 8 * (t + 256 * i);
        int row = o / K, k = o % K;
        int srow = row0 + row;
        uint4 v = make_uint4(0u, 0u, 0u, 0u);
        if (srow < n) v = *reinterpret_cast<const uint4*>(&A[(size_t)srow * K + k]);
        int gx = (k >> 3) ^ (row & 7);
        *reinterpret_cast<uint4*>(&As[row * K + gx * 8]) = v;
    }
    __syncthreads();

    int lane = t & 63, wv = t >> 6;
    int l15 = lane & 15, lhi = lane >> 4;
    f32x4 zero = {0.f, 0.f, 0.f, 0.f};
    f32x4 acc[4][4];
#pragma unroll
    for (int rf = 0; rf < 4; ++rf)
#pragma unroll
        for (int cf = 0; cf < 4; ++cf) acc[rf][cf] = zero;

#pragma unroll
    for (int s = 0; s < K / 32; ++s) {
        int g = 4 * s + lhi;
        short8 a[4], b[4];
#pragma unroll
        for (int rf = 0; rf < 4; ++rf) {
            int row = 16 * rf + l15;
            a[rf] = *reinterpret_cast<const short8*>(&As[row * K + (g ^ (row & 7)) * 8]);
        }
#pragma unroll
        for (int cf = 0; cf < 4; ++cf) {
            int c = 64 * wv + 16 * cf + l15;
            b[cf] = *reinterpret_cast<const short8*>(&Wf[((size_t)g * 256 + c) * 8]);
        }
#pragma unroll
        for (int rf = 0; rf < 4; ++rf)
#pragma unroll
            for (int cf = 0; cf < 4; ++cf)
                acc[rf][cf] = __builtin_amdgcn_mfma_f32_16x16x32_bf16(a[rf], b[cf], acc[rf][cf], 0, 0, 0);
    }

    if constexpr (EPI == 0) {  // bias + relu -> bf16, pi-packed
        unsigned short* H = (unsigned short*)outp;
        float bv[4];
#pragma unroll
        for (int cf = 0; cf < 4; ++cf) bv[cf] = bias[64 * wv + 16 * cf + l15];
#pragma unroll
        for (int rf = 0; rf < 4; ++rf) {
#pragma unroll
            for (int j = 0; j < 4; ++j) {
                int row = row0 + 16 * rf + 4 * lhi + j;
                if (row < n) {
                    float c0 = fmaxf(acc[rf][0][j] + bv[0], 0.f);
                    float c1 = fmaxf(acc[rf][1][j] + bv[1], 0.f);
                    float c2 = fmaxf(acc[rf][2][j] + bv[2], 0.f);
                    float c3 = fmaxf(acc[rf][3][j] + bv[3], 0.f);
                    uint2 o;
                    o.x = pk(c0, c1);
                    o.y = pk(c2, c3);
                    *reinterpret_cast<uint2*>(&H[(size_t)row * 256 + 64 * wv + 4 * l15]) = o;
                }
            }
        }
    } else {  // bias + row L2 normalize -> f32
        float* O = (float*)outp;
        float ss[4][4];
#pragma unroll
        for (int rf = 0; rf < 4; ++rf)
#pragma unroll
            for (int j = 0; j < 4; ++j) ss[rf][j] = 0.f;
#pragma unroll
        for (int cf = 0; cf < 4; ++cf) {
            int col = 64 * wv + 16 * cf + l15;
            float bc = bias[col];
#pragma unroll
            for (int rf = 0; rf < 4; ++rf)
#pragma unroll
                for (int j = 0; j < 4; ++j) {
                    float v = acc[rf][cf][j] + bc;
                    acc[rf][cf][j] = v;
                    ss[rf][j] = fmaf(v, v, ss[rf][j]);
                }
        }
#pragma unroll
        for (int rf = 0; rf < 4; ++rf)
#pragma unroll
            for (int j = 0; j < 4; ++j) {
#pragma unroll
                for (int off = 1; off <= 8; off <<= 1)
                    ss[rf][j] += __shfl_xor(ss[rf][j], off, 64);
            }
        if (l15 == 0) {
#pragma unroll
            for (int rf = 0; rf < 4; ++rf)
#pragma unroll
                for (int j = 0; j < 4; ++j) ssred[16 * rf + 4 * lhi + j][wv] = ss[rf][j];
        }
        __syncthreads();
        float rinv[4][4];
#pragma unroll
        for (int rf = 0; rf < 4; ++rf)
#pragma unroll
            for (int j = 0; j < 4; ++j) {
                float4 s4 = *reinterpret_cast<const float4*>(ssred[16 * rf + 4 * lhi + j]);
                float tot = s4.x + s4.y + s4.z + s4.w;
                rinv[rf][j] = 1.f / fmaxf(sqrtf(tot), 1e-12f);
            }
#pragma unroll
        for (int cf = 0; cf < 4; ++cf) {
            int col = 64 * wv + 16 * cf + l15;
#pragma unroll
            for (int rf = 0; rf < 4; ++rf)
#pragma unroll
                for (int j = 0; j < 4; ++j) {
                    int row = row0 + 16 * rf + 4 * lhi + j;
                    if (row < n)
                        __builtin_nontemporal_store(acc[rf][cf][j] * rinv[rf][j],
                                                    &O[(size_t)row * 256 + col]);
                }
        }
    }
}

extern "C" void kernel_launch(void* const* d_in, const int* in_sizes, int n_in,
                              void* d_out, int out_size, void* d_ws, size_t ws_size,
                              hipStream_t stream) {
    const float* x  = (const float*)d_in[0];
    const int*   ei = (const int*)d_in[1];
    const float* W1 = (const float*)d_in[2];
    const float* b1 = (const float*)d_in[3];
    const float* W2 = (const float*)d_in[4];
    const float* b2 = (const float*)d_in[5];
    float* out = (float*)d_out;

    const int N = NNODE;
    const int E = in_sizes[1] / 2;
    const int NB = (N + SCAN_CHUNK - 1) / SCAN_CHUNK;  // 25 <= 64

    char* ws = (char*)d_ws;
    size_t off = 0;
    auto alloc = [&](size_t bytes) -> void* {
        void* p = ws + off;
        off = (off + bytes + 255) & ~(size_t)255;
        return p;
    };
    unsigned int*   xb  = (unsigned int*)alloc((size_t)N * 128 * 2);    // x bf16
    unsigned int*   A1  = (unsigned int*)alloc((size_t)N * 128 * 2);    // agg(x)
    unsigned short* Bbf = (unsigned short*)alloc((size_t)N * FDIM * 2); // relu(gcn1), pi-order
    uint2*          A2  = (uint2*)alloc((size_t)N * FDIM * 2);          // agg(H1), pi-order
    unsigned short* Wf1 = (unsigned short*)alloc((size_t)16 * 256 * 8 * 2);
    unsigned short* Wf2 = (unsigned short*)alloc((size_t)32 * 256 * 8 * 2);
    int*   counts = (int*)alloc((size_t)N * 4);
    int*   rowp   = (int*)alloc((size_t)(N + 1) * 4);
    int*   cursor = (int*)alloc((size_t)N * 4);
    float* dinv   = (float*)alloc((size_t)N * 4);
    int2*  edata  = (int2*)alloc((size_t)E * 8);
    int*   bsum   = (int*)alloc((size_t)NB * 4);

    hipMemsetAsync(counts, 0, (size_t)N * 4, stream);
    int count_blocks = (E + 255) / 256;
    prep_kernel<<<CAST_BLOCKS + WCONV_BLOCKS + count_blocks, 256, 0, stream>>>(
        x, xb, W1, Wf1, W2, Wf2, ei, counts, E);
    scan_part1<<<NB, 256, 0, stream>>>(counts, bsum, N);
    scan_part3<<<NB, 256, 0, stream>>>(counts, bsum, rowp, cursor, dinv, N, NB);
    fill_kernel<<<(E + 255) / 256, 256, 0, stream>>>(ei, dinv, cursor, edata, E);

    agg1_kernel<<<(N * 64 + 255) / 256, 256, 0, stream>>>(xb, rowp, edata, dinv, A1, N);
    gemm_fused<128, 0><<<(N + 63) / 64, 256, 0, stream>>>(
        (const unsigned short*)A1, Wf1, b1, Bbf, N);
    agg2_kernel<<<(N * 64 + 255) / 256, 256, 0, stream>>>(
        (const uint2*)Bbf, rowp, edata, dinv, A2, N);
    gemm_fused<256, 1><<<(N + 63) / 64, 256, 0, stream>>>(
        (const unsigned short*)A2, Wf2, b2, out, N);
}

// Round 13
// 240.028 us; speedup vs baseline: 1.2421x; 1.2421x over previous
//
#include <hip/hip_runtime.h>
#include <hip/hip_bf16.h>

// GCN encoder: 2x GCNConv (sym-norm, self-loops) + ReLU + row L2 normalize.
// N=50000, E=800000, IN=128, HID=256, OUT=256.
// Aggregate-first: A1=agg(x_bf16); H1=relu(A1@W1+b1); A2=agg(H1);
// out=rownorm(A2@W2+b2). r10-form aggs (unroll-4, cached loads — r12 proved
// nt loads cost 1.5x), pi-permuted H1 columns, BM=128 512-thread MFMA GEMMs
// with fused epilogues.

#define NNODE 50000
#define FDIM 256
#define SCAN_CHUNK 2048
#define CAST_BLOCKS 3125   // N*128/8/256
#define WCONV_BLOCKS 48    // (16+32)*256/256

typedef __attribute__((ext_vector_type(8))) short short8;   // 8 bf16 (4 VGPRs)
typedef __attribute__((ext_vector_type(4))) float f32x4;    // MFMA acc

__device__ __forceinline__ float bflo(unsigned int u) {
    union { unsigned int i; float f; } c;
    c.i = u << 16;
    return c.f;
}
__device__ __forceinline__ float bfhi(unsigned int u) {
    union { unsigned int i; float f; } c;
    c.i = u & 0xFFFF0000u;
    return c.f;
}
__device__ __forceinline__ unsigned short f2bf(float f) {
    __hip_bfloat16 h = __float2bfloat16(f);  // RTN
    return *reinterpret_cast<unsigned short*>(&h);
}
__device__ __forceinline__ unsigned int pk(float lo, float hi) {
    return (unsigned int)f2bf(lo) | ((unsigned int)f2bf(hi) << 16);
}

// ---- prep: cast x->bf16, repack W1/W2, count degrees (independent jobs) --
// Wf2 uses permuted k: position k holds true feature f(k)=(k&~63)|((k&3)<<4)|((k>>2)&15)
// matching gemm1's packed epilogue position map p(f)=(f&~63)|((f&15)<<2)|((f>>4)&3).
__global__ __launch_bounds__(256) void prep_kernel(
    const float* __restrict__ x, unsigned int* __restrict__ xb,
    const float* __restrict__ W1, unsigned short* __restrict__ Wf1,
    const float* __restrict__ W2, unsigned short* __restrict__ Wf2,
    const int* __restrict__ ei, int* __restrict__ counts, int E) {
    int b = blockIdx.x, t = threadIdx.x;
    if (b < CAST_BLOCKS) {            // x[50000][128] fp32 -> bf16
        int i = b * 256 + t;          // 8 floats per thread, exact fit
        const float4* xf = reinterpret_cast<const float4*>(x);
        float4 p = xf[2 * i], q = xf[2 * i + 1];
        uint4 o;
        o.x = pk(p.x, p.y); o.y = pk(p.z, p.w);
        o.z = pk(q.x, q.y); o.w = pk(q.z, q.w);
        reinterpret_cast<uint4*>(xb)[i] = o;
    } else if (b < CAST_BLOCKS + WCONV_BLOCKS) {
        int idx = (b - CAST_BLOCKS) * 256 + t;
        const float* W;
        unsigned short* Wf;
        bool perm;
        if (idx < 16 * 256) { W = W1; Wf = Wf1; perm = false; }
        else { idx -= 16 * 256; W = W2; Wf = Wf2; perm = true; }
        int g = idx >> 8, c = idx & 255;
        unsigned short vals[8];
#pragma unroll
        for (int j = 0; j < 8; ++j) {
            int k = 8 * g + j;
            int f = perm ? ((k & ~63) | ((k & 3) << 4) | ((k >> 2) & 15)) : k;
            vals[j] = f2bf(W[(size_t)f * 256 + c]);
        }
        *reinterpret_cast<ushort4*>(&Wf[(size_t)idx * 8]) =
            make_ushort4(vals[0], vals[1], vals[2], vals[3]);
        *reinterpret_cast<ushort4*>(&Wf[(size_t)idx * 8 + 4]) =
            make_ushort4(vals[4], vals[5], vals[6], vals[7]);
    } else {                           // degree count
        int e = (b - CAST_BLOCKS - WCONV_BLOCKS) * 256 + t;
        if (e < E) atomicAdd(&counts[ei[E + e]], 1);
    }
}

// ---- scan: part1 per-chunk sums; part3 inlines the bsum scan (NB<=64) ---
__global__ __launch_bounds__(256) void scan_part1(const int* __restrict__ counts,
                                                  int* __restrict__ bsum, int n) {
    __shared__ int ws[4];
    int b = blockIdx.x, t = threadIdx.x;
    int base = b * SCAN_CHUNK + t * 8;
    int s = 0;
#pragma unroll
    for (int j = 0; j < 8; ++j) {
        int i = base + j;
        if (i < n) s += counts[i];
    }
#pragma unroll
    for (int off = 32; off >= 1; off >>= 1) s += __shfl_xor(s, off, 64);
    if ((t & 63) == 0) ws[t >> 6] = s;
    __syncthreads();
    if (t == 0) bsum[b] = ws[0] + ws[1] + ws[2] + ws[3];
}

__global__ __launch_bounds__(256) void scan_part3(const int* __restrict__ counts,
                                                  const int* __restrict__ bsum,
                                                  int* __restrict__ row_ptr,
                                                  int* __restrict__ cursor,
                                                  float* __restrict__ dinv,
                                                  int n, int nb) {
    __shared__ int ws[4];
    __shared__ int s_boff, s_total;
    int b = blockIdx.x, t = threadIdx.x, lane = t & 63, wid = t >> 6;
    if (t < 64) {  // wave 0: scan bsum (nb <= 64)
        int v = (t < nb) ? bsum[t] : 0;
        int incl = v;
#pragma unroll
        for (int off = 1; off < 64; off <<= 1) {
            int u = __shfl_up(incl, off, 64);
            if (t >= off) incl += u;
        }
        if (t == b) s_boff = incl - v;
        if (t == nb - 1) s_total = incl;
    }
    __syncthreads();
    if (b == 0 && t == 0) row_ptr[n] = s_total;

    int base = b * SCAN_CHUNK + t * 8;
    int v[8];
    int s = 0;
#pragma unroll
    for (int j = 0; j < 8; ++j) {
        int i = base + j;
        v[j] = (i < n) ? counts[i] : 0;
        s += v[j];
    }
    int incl = s;
#pragma unroll
    for (int off = 1; off < 64; off <<= 1) {
        int u = __shfl_up(incl, off, 64);
        if (lane >= off) incl += u;
    }
    if (lane == 63) ws[wid] = incl;
    __syncthreads();
    int woff = 0;
    for (int u = 0; u < wid; ++u) woff += ws[u];
    int ex = s_boff + woff + incl - s;
#pragma unroll
    for (int j = 0; j < 8; ++j) {
        int i = base + j;
        if (i < n) {
            row_ptr[i] = ex;
            cursor[i] = ex;
            dinv[i] = rsqrtf((float)(v[j] + 1));  // +1 self-loop
        }
        ex += v[j];
    }
}

// edata[pos] = {src, dinv[src]*dinv[dst]} (norm precomputed; r9 showed a
// dependent dinv[src] load in the gather chain costs ~15 us)
__global__ void fill_kernel(const int* __restrict__ ei, const float* __restrict__ dinv,
                            int* __restrict__ cursor, int2* __restrict__ edata, int E) {
    int e = blockIdx.x * blockDim.x + threadIdx.x;
    if (e < E) {
        int s = ei[e];
        int d = ei[E + e];
        int pos = atomicAdd(&cursor[d], 1);
        float nm = dinv[s] * dinv[d];
        edata[pos] = make_int2(s, __float_as_int(nm));
    }
}

// ---- agg1: A1[i] = sum nm*xb[src] + dinv_i^2*xb[i]  (128 feats, 256B rows)
// r10-form: wave per node, plain unroll-4, cached loads (nt hurts: r12).
__global__ __launch_bounds__(256) void agg1_kernel(const unsigned int* __restrict__ xb,
                                                   const int* __restrict__ rowp,
                                                   const int2* __restrict__ edata,
                                                   const float* __restrict__ dinv,
                                                   unsigned int* __restrict__ A1, int n) {
    int node = (blockIdx.x * blockDim.x + threadIdx.x) >> 6;
    int lane = threadIdx.x & 63;
    if (node >= n) return;
    float di = dinv[node];
    float d2 = di * di;
    unsigned int sv = xb[(size_t)node * 64 + lane];
    float a0 = bflo(sv) * d2, a1 = bfhi(sv) * d2;
    int beg = rowp[node], end = rowp[node + 1];
#pragma unroll 4
    for (int e = beg; e < end; ++e) {
        int2 ed = edata[e];
        float nm = __int_as_float(ed.y);
        unsigned int v = xb[(size_t)ed.x * 64 + lane];
        a0 = fmaf(bflo(v), nm, a0);
        a1 = fmaf(bfhi(v), nm, a1);
    }
    A1[(size_t)node * 64 + lane] = pk(a0, a1);
}

// ---- agg2: A2[i] = sum nm*hb[src] + dinv_i^2*hb[i]  (256 feats, 512B rows)
__global__ __launch_bounds__(256) void agg2_kernel(const uint2* __restrict__ hb,
                                                   const int* __restrict__ rowp,
                                                   const int2* __restrict__ edata,
                                                   const float* __restrict__ dinv,
                                                   uint2* __restrict__ A2, int n) {
    int node = (blockIdx.x * blockDim.x + threadIdx.x) >> 6;
    int lane = threadIdx.x & 63;
    if (node >= n) return;
    float di = dinv[node];
    float d2 = di * di;
    uint2 sv = hb[(size_t)node * 64 + lane];
    float a0 = bflo(sv.x) * d2, a1 = bfhi(sv.x) * d2;
    float a2 = bflo(sv.y) * d2, a3 = bfhi(sv.y) * d2;
    int beg = rowp[node], end = rowp[node + 1];
#pragma unroll 4
    for (int e = beg; e < end; ++e) {
        int2 ed = edata[e];
        float nm = __int_as_float(ed.y);
        uint2 v = hb[(size_t)ed.x * 64 + lane];
        a0 = fmaf(bflo(v.x), nm, a0);
        a1 = fmaf(bfhi(v.x), nm, a1);
        a2 = fmaf(bflo(v.y), nm, a2);
        a3 = fmaf(bfhi(v.y), nm, a3);
    }
    uint2 o;
    o.x = pk(a0, a1);
    o.y = pk(a2, a3);
    A2[(size_t)node * 64 + lane] = o;
}

// ---- MFMA GEMM + fused epilogue: out = f(A[n,K] @ W[K,256] + bias) ------
// BM=128, BN=256, 512 threads = 8 waves in 2x4; wave = 64x64.
// EPI 0: relu -> bf16 H in pi-permuted column order (packed uint2 stores).
// EPI 1: row L2-normalize -> f32 out (true order, nontemporal).
template <int K, int EPI>
__global__ __launch_bounds__(512) void gemm_fused(const unsigned short* __restrict__ A,
                                                  const unsigned short* __restrict__ Wf,
                                                  const float* __restrict__ bias,
                                                  void* __restrict__ outp, int n) {
    __shared__ unsigned short As[128 * K];
    __shared__ __align__(16) float ssred[128][4];
    int t = threadIdx.x;
    int row0 = blockIdx.x * 128;

#pragma unroll
    for (int i = 0; i < (128 * K) / (8 * 512); ++i) {
        int o = 8 * (t + 512 * i);
        int row = o / K, k = o % K;
        int srow = row0 + row;
        uint4 v = make_uint4(0u, 0u, 0u, 0u);
        if (srow < n) v = *reinterpret_cast<const uint4*>(&A[(size_t)srow * K + k]);
        int gx = (k >> 3) ^ (row & 7);
        *reinterpret_cast<uint4*>(&As[row * K + gx * 8]) = v;
    }
    __syncthreads();

    int lane = t & 63, wv = t >> 6;
    int rw = wv >> 2, cw = wv & 3;  // 2x4 waves
    int l15 = lane & 15, lhi = lane >> 4;
    f32x4 zero = {0.f, 0.f, 0.f, 0.f};
    f32x4 acc[4][4];
#pragma unroll
    for (int rf = 0; rf < 4; ++rf)
#pragma unroll
        for (int cf = 0; cf < 4; ++cf) acc[rf][cf] = zero;

#pragma unroll
    for (int s = 0; s < K / 32; ++s) {
        int g = 4 * s + lhi;
        short8 a[4], b[4];
#pragma unroll
        for (int rf = 0; rf < 4; ++rf) {
            int row = 64 * rw + 16 * rf + l15;
            a[rf] = *reinterpret_cast<const short8*>(&As[row * K + (g ^ (row & 7)) * 8]);
        }
#pragma unroll
        for (int cf = 0; cf < 4; ++cf) {
            int c = 64 * cw + 16 * cf + l15;
            b[cf] = *reinterpret_cast<const short8*>(&Wf[((size_t)g * 256 + c) * 8]);
        }
#pragma unroll
        for (int rf = 0; rf < 4; ++rf)
#pragma unroll
            for (int cf = 0; cf < 4; ++cf)
                acc[rf][cf] = __builtin_amdgcn_mfma_f32_16x16x32_bf16(a[rf], b[cf], acc[rf][cf], 0, 0, 0);
    }

    if constexpr (EPI == 0) {  // bias + relu -> bf16, pi-packed
        unsigned short* H = (unsigned short*)outp;
        float bv[4];
#pragma unroll
        for (int cf = 0; cf < 4; ++cf) bv[cf] = bias[64 * cw + 16 * cf + l15];
#pragma unroll
        for (int rf = 0; rf < 4; ++rf) {
#pragma unroll
            for (int j = 0; j < 4; ++j) {
                int row = row0 + 64 * rw + 16 * rf + 4 * lhi + j;
                if (row < n) {
                    float c0 = fmaxf(acc[rf][0][j] + bv[0], 0.f);
                    float c1 = fmaxf(acc[rf][1][j] + bv[1], 0.f);
                    float c2 = fmaxf(acc[rf][2][j] + bv[2], 0.f);
                    float c3 = fmaxf(acc[rf][3][j] + bv[3], 0.f);
                    uint2 o;
                    o.x = pk(c0, c1);
                    o.y = pk(c2, c3);
                    *reinterpret_cast<uint2*>(&H[(size_t)row * 256 + 64 * cw + 4 * l15]) = o;
                }
            }
        }
    } else {  // bias + row L2 normalize -> f32
        float* O = (float*)outp;
        float ss[4][4];
#pragma unroll
        for (int rf = 0; rf < 4; ++rf)
#pragma unroll
            for (int j = 0; j < 4; ++j) ss[rf][j] = 0.f;
#pragma unroll
        for (int cf = 0; cf < 4; ++cf) {
            int col = 64 * cw + 16 * cf + l15;
            float bc = bias[col];
#pragma unroll
            for (int rf = 0; rf < 4; ++rf)
#pragma unroll
                for (int j = 0; j < 4; ++j) {
                    float v = acc[rf][cf][j] + bc;
                    acc[rf][cf][j] = v;
                    ss[rf][j] = fmaf(v, v, ss[rf][j]);
                }
        }
#pragma unroll
        for (int rf = 0; rf < 4; ++rf)
#pragma unroll
            for (int j = 0; j < 4; ++j) {
#pragma unroll
                for (int off = 1; off <= 8; off <<= 1)
                    ss[rf][j] += __shfl_xor(ss[rf][j], off, 64);
            }
        if (l15 == 0) {
#pragma unroll
            for (int rf = 0; rf < 4; ++rf)
#pragma unroll
                for (int j = 0; j < 4; ++j)
                    ssred[64 * rw + 16 * rf + 4 * lhi + j][cw] = ss[rf][j];
        }
        __syncthreads();
        float rinv[4][4];
#pragma unroll
        for (int rf = 0; rf < 4; ++rf)
#pragma unroll
            for (int j = 0; j < 4; ++j) {
                float4 s4 = *reinterpret_cast<const float4*>(
                    ssred[64 * rw + 16 * rf + 4 * lhi + j]);
                float tot = s4.x + s4.y + s4.z + s4.w;
                rinv[rf][j] = 1.f / fmaxf(sqrtf(tot), 1e-12f);
            }
#pragma unroll
        for (int cf = 0; cf < 4; ++cf) {
            int col = 64 * cw + 16 * cf + l15;
#pragma unroll
            for (int rf = 0; rf < 4; ++rf)
#pragma unroll
                for (int j = 0; j < 4; ++j) {
                    int row = row0 + 64 * rw + 16 * rf + 4 * lhi + j;
                    if (row < n)
                        __builtin_nontemporal_store(acc[rf][cf][j] * rinv[rf][j],
                                                    &O[(size_t)row * 256 + col]);
                }
        }
    }
}

extern "C" void kernel_launch(void* const* d_in, const int* in_sizes, int n_in,
                              void* d_out, int out_size, void* d_ws, size_t ws_size,
                              hipStream_t stream) {
    const float* x  = (const float*)d_in[0];
    const int*   ei = (const int*)d_in[1];
    const float* W1 = (const float*)d_in[2];
    const float* b1 = (const float*)d_in[3];
    const float* W2 = (const float*)d_in[4];
    const float* b2 = (const float*)d_in[5];
    float* out = (float*)d_out;

    const int N = NNODE;
    const int E = in_sizes[1] / 2;
    const int NB = (N + SCAN_CHUNK - 1) / SCAN_CHUNK;  // 25 <= 64

    char* ws = (char*)d_ws;
    size_t off = 0;
    auto alloc = [&](size_t bytes) -> void* {
        void* p = ws + off;
        off = (off + bytes + 255) & ~(size_t)255;
        return p;
    };
    unsigned int*   xb  = (unsigned int*)alloc((size_t)N * 128 * 2);    // x bf16
    unsigned int*   A1  = (unsigned int*)alloc((size_t)N * 128 * 2);    // agg(x)
    unsigned short* Bbf = (unsigned short*)alloc((size_t)N * FDIM * 2); // relu(gcn1), pi-order
    uint2*          A2  = (uint2*)alloc((size_t)N * FDIM * 2);          // agg(H1), pi-order
    unsigned short* Wf1 = (unsigned short*)alloc((size_t)16 * 256 * 8 * 2);
    unsigned short* Wf2 = (unsigned short*)alloc((size_t)32 * 256 * 8 * 2);
    int*   counts = (int*)alloc((size_t)N * 4);
    int*   rowp   = (int*)alloc((size_t)(N + 1) * 4);
    int*   cursor = (int*)alloc((size_t)N * 4);
    float* dinv   = (float*)alloc((size_t)N * 4);
    int2*  edata  = (int2*)alloc((size_t)E * 8);
    int*   bsum   = (int*)alloc((size_t)NB * 4);

    hipMemsetAsync(counts, 0, (size_t)N * 4, stream);
    int count_blocks = (E + 255) / 256;
    prep_kernel<<<CAST_BLOCKS + WCONV_BLOCKS + count_blocks, 256, 0, stream>>>(
        x, xb, W1, Wf1, W2, Wf2, ei, counts, E);
    scan_part1<<<NB, 256, 0, stream>>>(counts, bsum, N);
    scan_part3<<<NB, 256, 0, stream>>>(counts, bsum, rowp, cursor, dinv, N, NB);
    fill_kernel<<<(E + 255) / 256, 256, 0, stream>>>(ei, dinv, cursor, edata, E);

    agg1_kernel<<<(N * 64 + 255) / 256, 256, 0, stream>>>(xb, rowp, edata, dinv, A1, N);
    gemm_fused<128, 0><<<(N + 127) / 128, 512, 0, stream>>>(
        (const unsigned short*)A1, Wf1, b1, Bbf, N);
    agg2_kernel<<<(N * 64 + 255) / 256, 256, 0, stream>>>(
        (const uint2*)Bbf, rowp, edata, dinv, A2, N);
    gemm_fused<256, 1><<<(N + 127) / 128, 512, 0, stream>>>(
        (const unsigned short*)A2, Wf2, b2, out, N);
}

// Round 14
// 237.564 us; speedup vs baseline: 1.2550x; 1.0104x over previous
//
#include <hip/hip_runtime.h>
#include <hip/hip_bf16.h>

// GCN encoder: 2x GCNConv (sym-norm, self-loops) + ReLU + row L2 normalize.
// N=50000, E=800000, IN=128, HID=256, OUT=256.
// Aggregate-first + PHASE-SORTED gathers: each node's edge list is
// counting-sorted by src>>12 (13 phases x 4096 nodes) so concurrent waves
// sweep the source array in ~2MB windows -> per-XCD L2-resident.
// r13 aggs/GEMMs otherwise unchanged (BM=128 512-thread MFMA, fused epilogues).

#define NNODE 50000
#define FDIM 256
#define NPH 13            // ceil(50000/4096)
#define PHSH 12           // phase = src >> 12
#define NCNT (NNODE * NPH)
#define SCAN_CHUNK 2048
#define CAST_BLOCKS 3125   // N*128/8/256
#define WCONV_BLOCKS 48    // (16+32)*256/256

typedef __attribute__((ext_vector_type(8))) short short8;   // 8 bf16 (4 VGPRs)
typedef __attribute__((ext_vector_type(4))) float f32x4;    // MFMA acc

__device__ __forceinline__ float bflo(unsigned int u) {
    union { unsigned int i; float f; } c;
    c.i = u << 16;
    return c.f;
}
__device__ __forceinline__ float bfhi(unsigned int u) {
    union { unsigned int i; float f; } c;
    c.i = u & 0xFFFF0000u;
    return c.f;
}
__device__ __forceinline__ unsigned short f2bf(float f) {
    __hip_bfloat16 h = __float2bfloat16(f);  // RTN
    return *reinterpret_cast<unsigned short*>(&h);
}
__device__ __forceinline__ unsigned int pk(float lo, float hi) {
    return (unsigned int)f2bf(lo) | ((unsigned int)f2bf(hi) << 16);
}

// ---- prep: cast x->bf16, repack W1/W2, count (dst,phase) degrees ---------
__global__ __launch_bounds__(256) void prep_kernel(
    const float* __restrict__ x, unsigned int* __restrict__ xb,
    const float* __restrict__ W1, unsigned short* __restrict__ Wf1,
    const float* __restrict__ W2, unsigned short* __restrict__ Wf2,
    const int* __restrict__ ei, int* __restrict__ counts, int E) {
    int b = blockIdx.x, t = threadIdx.x;
    if (b < CAST_BLOCKS) {            // x[50000][128] fp32 -> bf16
        int i = b * 256 + t;          // 8 floats per thread, exact fit
        const float4* xf = reinterpret_cast<const float4*>(x);
        float4 p = xf[2 * i], q = xf[2 * i + 1];
        uint4 o;
        o.x = pk(p.x, p.y); o.y = pk(p.z, p.w);
        o.z = pk(q.x, q.y); o.w = pk(q.z, q.w);
        reinterpret_cast<uint4*>(xb)[i] = o;
    } else if (b < CAST_BLOCKS + WCONV_BLOCKS) {
        // Wf[g][col][j]=bf16(W[f(8g+j)][col]); Wf2 permuted to match gemm1's
        // packed epilogue: f(k)=(k&~63)|((k&3)<<4)|((k>>2)&15).
        int idx = (b - CAST_BLOCKS) * 256 + t;
        const float* W;
        unsigned short* Wf;
        bool perm;
        if (idx < 16 * 256) { W = W1; Wf = Wf1; perm = false; }
        else { idx -= 16 * 256; W = W2; Wf = Wf2; perm = true; }
        int g = idx >> 8, c = idx & 255;
        unsigned short vals[8];
#pragma unroll
        for (int j = 0; j < 8; ++j) {
            int k = 8 * g + j;
            int f = perm ? ((k & ~63) | ((k & 3) << 4) | ((k >> 2) & 15)) : k;
            vals[j] = f2bf(W[(size_t)f * 256 + c]);
        }
        *reinterpret_cast<ushort4*>(&Wf[(size_t)idx * 8]) =
            make_ushort4(vals[0], vals[1], vals[2], vals[3]);
        *reinterpret_cast<ushort4*>(&Wf[(size_t)idx * 8 + 4]) =
            make_ushort4(vals[4], vals[5], vals[6], vals[7]);
    } else {                           // (dst, src-phase) count
        int e = (b - CAST_BLOCKS - WCONV_BLOCKS) * 256 + t;
        if (e < E) {
            int s = ei[e];
            int d = ei[E + e];
            atomicAdd(&counts[d * NPH + (s >> PHSH)], 1);
        }
    }
}

// ---- 3-level exclusive scan over NCNT=650000 counters -------------------
__global__ __launch_bounds__(256) void scan_part1(const int* __restrict__ counts,
                                                  int* __restrict__ bsum, int m) {
    __shared__ int ws[4];
    int b = blockIdx.x, t = threadIdx.x;
    int base = b * SCAN_CHUNK + t * 8;
    int s = 0;
#pragma unroll
    for (int j = 0; j < 8; ++j) {
        int i = base + j;
        if (i < m) s += counts[i];
    }
#pragma unroll
    for (int off = 32; off >= 1; off >>= 1) s += __shfl_xor(s, off, 64);
    if ((t & 63) == 0) ws[t >> 6] = s;
    __syncthreads();
    if (t == 0) bsum[b] = ws[0] + ws[1] + ws[2] + ws[3];
}

// single 64-thread block: serial-carry wave scan over nb block sums
__global__ void scan_part2(const int* __restrict__ bsum, int* __restrict__ boff,
                           int* __restrict__ row_ptr, int nb, int m) {
    int l = threadIdx.x;
    int carry = 0;
    for (int base = 0; base < nb; base += 64) {
        int i = base + l;
        int v = (i < nb) ? bsum[i] : 0;
        int incl = v;
#pragma unroll
        for (int off = 1; off < 64; off <<= 1) {
            int u = __shfl_up(incl, off, 64);
            if (l >= off) incl += u;
        }
        if (i < nb) boff[i] = carry + incl - v;
        carry += __shfl(incl, 63, 64);
    }
    if (l == 0) row_ptr[m] = carry;  // == E
}

__global__ __launch_bounds__(256) void scan_part3(const int* __restrict__ counts,
                                                  const int* __restrict__ boff,
                                                  int* __restrict__ row_ptr,
                                                  int* __restrict__ cursor, int m) {
    __shared__ int ws[4];
    int b = blockIdx.x, t = threadIdx.x, lane = t & 63, wid = t >> 6;
    int base = b * SCAN_CHUNK + t * 8;
    int v[8];
    int s = 0;
#pragma unroll
    for (int j = 0; j < 8; ++j) {
        int i = base + j;
        v[j] = (i < m) ? counts[i] : 0;
        s += v[j];
    }
    int incl = s;
#pragma unroll
    for (int off = 1; off < 64; off <<= 1) {
        int u = __shfl_up(incl, off, 64);
        if (lane >= off) incl += u;
    }
    if (lane == 63) ws[wid] = incl;
    __syncthreads();
    int woff = 0;
    for (int u = 0; u < wid; ++u) woff += ws[u];
    int ex = boff[b] + woff + incl - s;
#pragma unroll
    for (int j = 0; j < 8; ++j) {
        int i = base + j;
        if (i < m) { row_ptr[i] = ex; cursor[i] = ex; }
        ex += v[j];
    }
}

// dinv[i] = rsqrt(deg_i + 1); deg from scanned (node,phase) offsets
__global__ void dinv_kernel(const int* __restrict__ rowp, float* __restrict__ dinv, int n) {
    int i = blockIdx.x * blockDim.x + threadIdx.x;
    if (i < n) {
        int deg = rowp[(i + 1) * NPH] - rowp[i * NPH];
        dinv[i] = rsqrtf((float)(deg + 1));
    }
}

// edata[pos] = {src, dinv[src]*dinv[dst]}; pos bucketed by (dst, src-phase)
__global__ void fill_kernel(const int* __restrict__ ei, const float* __restrict__ dinv,
                            int* __restrict__ cursor, int2* __restrict__ edata, int E) {
    int e = blockIdx.x * blockDim.x + threadIdx.x;
    if (e < E) {
        int s = ei[e];
        int d = ei[E + e];
        int pos = atomicAdd(&cursor[d * NPH + (s >> PHSH)], 1);
        float nm = dinv[s] * dinv[d];
        edata[pos] = make_int2(s, __float_as_int(nm));
    }
}

// ---- agg1: A1[i] = sum nm*xb[src] + dinv_i^2*xb[i]  (128 feats, 256B rows)
// Edge range [rowp[n*NPH], rowp[(n+1)*NPH]) is contiguous, phase-sorted.
__global__ __launch_bounds__(256) void agg1_kernel(const unsigned int* __restrict__ xb,
                                                   const int* __restrict__ rowp,
                                                   const int2* __restrict__ edata,
                                                   const float* __restrict__ dinv,
                                                   unsigned int* __restrict__ A1, int n) {
    int node = (blockIdx.x * blockDim.x + threadIdx.x) >> 6;
    int lane = threadIdx.x & 63;
    if (node >= n) return;
    float di = dinv[node];
    float d2 = di * di;
    unsigned int sv = xb[(size_t)node * 64 + lane];
    float a0 = bflo(sv) * d2, a1 = bfhi(sv) * d2;
    int beg = rowp[node * NPH], end = rowp[node * NPH + NPH];
#pragma unroll 4
    for (int e = beg; e < end; ++e) {
        int2 ed = edata[e];
        float nm = __int_as_float(ed.y);
        unsigned int v = xb[(size_t)ed.x * 64 + lane];
        a0 = fmaf(bflo(v), nm, a0);
        a1 = fmaf(bfhi(v), nm, a1);
    }
    A1[(size_t)node * 64 + lane] = pk(a0, a1);
}

// ---- agg2: A2[i] = sum nm*hb[src] + dinv_i^2*hb[i]  (256 feats, 512B rows)
__global__ __launch_bounds__(256) void agg2_kernel(const uint2* __restrict__ hb,
                                                   const int* __restrict__ rowp,
                                                   const int2* __restrict__ edata,
                                                   const float* __restrict__ dinv,
                                                   uint2* __restrict__ A2, int n) {
    int node = (blockIdx.x * blockDim.x + threadIdx.x) >> 6;
    int lane = threadIdx.x & 63;
    if (node >= n) return;
    float di = dinv[node];
    float d2 = di * di;
    uint2 sv = hb[(size_t)node * 64 + lane];
    float a0 = bflo(sv.x) * d2, a1 = bfhi(sv.x) * d2;
    float a2 = bflo(sv.y) * d2, a3 = bfhi(sv.y) * d2;
    int beg = rowp[node * NPH], end = rowp[node * NPH + NPH];
#pragma unroll 4
    for (int e = beg; e < end; ++e) {
        int2 ed = edata[e];
        float nm = __int_as_float(ed.y);
        uint2 v = hb[(size_t)ed.x * 64 + lane];
        a0 = fmaf(bflo(v.x), nm, a0);
        a1 = fmaf(bfhi(v.x), nm, a1);
        a2 = fmaf(bflo(v.y), nm, a2);
        a3 = fmaf(bfhi(v.y), nm, a3);
    }
    uint2 o;
    o.x = pk(a0, a1);
    o.y = pk(a2, a3);
    A2[(size_t)node * 64 + lane] = o;
}

// ---- MFMA GEMM + fused epilogue: out = f(A[n,K] @ W[K,256] + bias) ------
// BM=128, BN=256, 512 threads = 8 waves in 2x4; wave = 64x64.
// EPI 0: relu -> bf16 H in pi-permuted column order (packed uint2 stores).
// EPI 1: row L2-normalize -> f32 out (true order, nontemporal).
template <int K, int EPI>
__global__ __launch_bounds__(512) void gemm_fused(const unsigned short* __restrict__ A,
                                                  const unsigned short* __restrict__ Wf,
                                                  const float* __restrict__ bias,
                                                  void* __restrict__ outp, int n) {
    __shared__ unsigned short As[128 * K];
    __shared__ __align__(16) float ssred[128][4];
    int t = threadIdx.x;
    int row0 = blockIdx.x * 128;

#pragma unroll
    for (int i = 0; i < (128 * K) / (8 * 512); ++i) {
        int o = 8 * (t + 512 * i);
        int row = o / K, k = o % K;
        int srow = row0 + row;
        uint4 v = make_uint4(0u, 0u, 0u, 0u);
        if (srow < n) v = *reinterpret_cast<const uint4*>(&A[(size_t)srow * K + k]);
        int gx = (k >> 3) ^ (row & 7);
        *reinterpret_cast<uint4*>(&As[row * K + gx * 8]) = v;
    }
    __syncthreads();

    int lane = t & 63, wv = t >> 6;
    int rw = wv >> 2, cw = wv & 3;  // 2x4 waves
    int l15 = lane & 15, lhi = lane >> 4;
    f32x4 zero = {0.f, 0.f, 0.f, 0.f};
    f32x4 acc[4][4];
#pragma unroll
    for (int rf = 0; rf < 4; ++rf)
#pragma unroll
        for (int cf = 0; cf < 4; ++cf) acc[rf][cf] = zero;

#pragma unroll
    for (int s = 0; s < K / 32; ++s) {
        int g = 4 * s + lhi;
        short8 a[4], b[4];
#pragma unroll
        for (int rf = 0; rf < 4; ++rf) {
            int row = 64 * rw + 16 * rf + l15;
            a[rf] = *reinterpret_cast<const short8*>(&As[row * K + (g ^ (row & 7)) * 8]);
        }
#pragma unroll
        for (int cf = 0; cf < 4; ++cf) {
            int c = 64 * cw + 16 * cf + l15;
            b[cf] = *reinterpret_cast<const short8*>(&Wf[((size_t)g * 256 + c) * 8]);
        }
#pragma unroll
        for (int rf = 0; rf < 4; ++rf)
#pragma unroll
            for (int cf = 0; cf < 4; ++cf)
                acc[rf][cf] = __builtin_amdgcn_mfma_f32_16x16x32_bf16(a[rf], b[cf], acc[rf][cf], 0, 0, 0);
    }

    if constexpr (EPI == 0) {  // bias + relu -> bf16, pi-packed
        unsigned short* H = (unsigned short*)outp;
        float bv[4];
#pragma unroll
        for (int cf = 0; cf < 4; ++cf) bv[cf] = bias[64 * cw + 16 * cf + l15];
#pragma unroll
        for (int rf = 0; rf < 4; ++rf) {
#pragma unroll
            for (int j = 0; j < 4; ++j) {
                int row = row0 + 64 * rw + 16 * rf + 4 * lhi + j;
                if (row < n) {
                    float c0 = fmaxf(acc[rf][0][j] + bv[0], 0.f);
                    float c1 = fmaxf(acc[rf][1][j] + bv[1], 0.f);
                    float c2 = fmaxf(acc[rf][2][j] + bv[2], 0.f);
                    float c3 = fmaxf(acc[rf][3][j] + bv[3], 0.f);
                    uint2 o;
                    o.x = pk(c0, c1);
                    o.y = pk(c2, c3);
                    *reinterpret_cast<uint2*>(&H[(size_t)row * 256 + 64 * cw + 4 * l15]) = o;
                }
            }
        }
    } else {  // bias + row L2 normalize -> f32
        float* O = (float*)outp;
        float ss[4][4];
#pragma unroll
        for (int rf = 0; rf < 4; ++rf)
#pragma unroll
            for (int j = 0; j < 4; ++j) ss[rf][j] = 0.f;
#pragma unroll
        for (int cf = 0; cf < 4; ++cf) {
            int col = 64 * cw + 16 * cf + l15;
            float bc = bias[col];
#pragma unroll
            for (int rf = 0; rf < 4; ++rf)
#pragma unroll
                for (int j = 0; j < 4; ++j) {
                    float v = acc[rf][cf][j] + bc;
                    acc[rf][cf][j] = v;
                    ss[rf][j] = fmaf(v, v, ss[rf][j]);
                }
        }
#pragma unroll
        for (int rf = 0; rf < 4; ++rf)
#pragma unroll
            for (int j = 0; j < 4; ++j) {
#pragma unroll
                for (int off = 1; off <= 8; off <<= 1)
                    ss[rf][j] += __shfl_xor(ss[rf][j], off, 64);
            }
        if (l15 == 0) {
#pragma unroll
            for (int rf = 0; rf < 4; ++rf)
#pragma unroll
                for (int j = 0; j < 4; ++j)
                    ssred[64 * rw + 16 * rf + 4 * lhi + j][cw] = ss[rf][j];
        }
        __syncthreads();
        float rinv[4][4];
#pragma unroll
        for (int rf = 0; rf < 4; ++rf)
#pragma unroll
            for (int j = 0; j < 4; ++j) {
                float4 s4 = *reinterpret_cast<const float4*>(
                    ssred[64 * rw + 16 * rf + 4 * lhi + j]);
                float tot = s4.x + s4.y + s4.z + s4.w;
                rinv[rf][j] = 1.f / fmaxf(sqrtf(tot), 1e-12f);
            }
#pragma unroll
        for (int cf = 0; cf < 4; ++cf) {
            int col = 64 * cw + 16 * cf + l15;
#pragma unroll
            for (int rf = 0; rf < 4; ++rf)
#pragma unroll
                for (int j = 0; j < 4; ++j) {
                    int row = row0 + 64 * rw + 16 * rf + 4 * lhi + j;
                    if (row < n)
                        __builtin_nontemporal_store(acc[rf][cf][j] * rinv[rf][j],
                                                    &O[(size_t)row * 256 + col]);
                }
        }
    }
}

extern "C" void kernel_launch(void* const* d_in, const int* in_sizes, int n_in,
                              void* d_out, int out_size, void* d_ws, size_t ws_size,
                              hipStream_t stream) {
    const float* x  = (const float*)d_in[0];
    const int*   ei = (const int*)d_in[1];
    const float* W1 = (const float*)d_in[2];
    const float* b1 = (const float*)d_in[3];
    const float* W2 = (const float*)d_in[4];
    const float* b2 = (const float*)d_in[5];
    float* out = (float*)d_out;

    const int N = NNODE;
    const int E = in_sizes[1] / 2;
    const int M = NCNT;                                   // 650000 counters
    const int NB = (M + SCAN_CHUNK - 1) / SCAN_CHUNK;     // 318

    char* ws = (char*)d_ws;
    size_t off = 0;
    auto alloc = [&](size_t bytes) -> void* {
        void* p = ws + off;
        off = (off + bytes + 255) & ~(size_t)255;
        return p;
    };
    unsigned int*   xb  = (unsigned int*)alloc((size_t)N * 128 * 2);    // x bf16
    unsigned int*   A1  = (unsigned int*)alloc((size_t)N * 128 * 2);    // agg(x)
    unsigned short* Bbf = (unsigned short*)alloc((size_t)N * FDIM * 2); // relu(gcn1), pi-order
    uint2*          A2  = (uint2*)alloc((size_t)N * FDIM * 2);          // agg(H1), pi-order
    unsigned short* Wf1 = (unsigned short*)alloc((size_t)16 * 256 * 8 * 2);
    unsigned short* Wf2 = (unsigned short*)alloc((size_t)32 * 256 * 8 * 2);
    int*   counts = (int*)alloc((size_t)M * 4);
    int*   rowp   = (int*)alloc((size_t)(M + 1) * 4);
    int*   cursor = (int*)alloc((size_t)M * 4);
    float* dinv   = (float*)alloc((size_t)N * 4);
    int2*  edata  = (int2*)alloc((size_t)E * 8);
    int*   bsum   = (int*)alloc((size_t)NB * 4);
    int*   boff   = (int*)alloc((size_t)NB * 4);

    hipMemsetAsync(counts, 0, (size_t)M * 4, stream);
    int count_blocks = (E + 255) / 256;
    prep_kernel<<<CAST_BLOCKS + WCONV_BLOCKS + count_blocks, 256, 0, stream>>>(
        x, xb, W1, Wf1, W2, Wf2, ei, counts, E);
    scan_part1<<<NB, 256, 0, stream>>>(counts, bsum, M);
    scan_part2<<<1, 64, 0, stream>>>(bsum, boff, rowp, NB, M);
    scan_part3<<<NB, 256, 0, stream>>>(counts, boff, rowp, cursor, M);
    dinv_kernel<<<(N + 255) / 256, 256, 0, stream>>>(rowp, dinv, N);
    fill_kernel<<<(E + 255) / 256, 256, 0, stream>>>(ei, dinv, cursor, edata, E);

    agg1_kernel<<<(N * 64 + 255) / 256, 256, 0, stream>>>(xb, rowp, edata, dinv, A1, N);
    gemm_fused<128, 0><<<(N + 127) / 128, 512, 0, stream>>>(
        (const unsigned short*)A1, Wf1, b1, Bbf, N);
    agg2_kernel<<<(N * 64 + 255) / 256, 256, 0, stream>>>(
        (const uint2*)Bbf, rowp, edata, dinv, A2, N);
    gemm_fused<256, 1><<<(N + 127) / 128, 512, 0, stream>>>(
        (const unsigned short*)A2, Wf2, b2, out, N);
}